// Round 10
// baseline (51.253 us; speedup 1.0000x reference)
//
#include <hip/hip_runtime.h>
#include <hip/hip_bf16.h>
#include <math.h>

#define WINDOW 50

typedef __attribute__((ext_vector_type(8))) short short8;
typedef __attribute__((ext_vector_type(4))) float f32x4;
typedef unsigned int uint;

union U8 { uint4 u; short8 s; };
union UF4 { uint4 u; f32x4 f; };
__device__ inline short8 as_s8(uint4 u) { U8 t; t.u = u; return t.s; }
__device__ inline f32x4  as_f4(uint4 u) { UF4 t; t.u = u; return t.f; }

__device__ inline uint pk2(float a, float b) {
    uint r;
    asm("v_cvt_pk_bf16_f32 %0, %1, %2" : "=v"(r) : "v"(a), "v"(b));
    return r;
}
__device__ inline float lo_f32(uint u) { return __uint_as_float(u << 16); }
__device__ inline float hi_f32(uint u) { return __uint_as_float(u & 0xffff0000u); }

#define LDS_FENCE() do { asm volatile("s_waitcnt lgkmcnt(0)" ::: "memory"); \
                         __builtin_amdgcn_sched_barrier(0); } while (0)

// ---------------- prep: weight fragments into ws[0..18*64) ----------------
__global__ __launch_bounds__(64) void nsg_prep(
    const float* __restrict__ w1, const float* __restrict__ b1,
    const float* __restrict__ w2, const float* __restrict__ b2,
    const float* __restrict__ w3, uint4* __restrict__ ws)
{
    const int wl  = threadIdx.x;
    const int l15 = wl & 15;
    const int g   = wl >> 4;

    #pragma unroll
    for (int nt = 0; nt < 4; ++nt) {
        int n = nt * 16 + l15;
        float a = w1[n], b = w1[64 + n], c = w1[128 + n], d = w1[192 + n];
        uint hab = pk2(a, b), hcd = pk2(c, d);
        uint lab = pk2(a - lo_f32(hab), b - hi_f32(hab));
        uint lcd = pk2(c - lo_f32(hcd), d - hi_f32(hcd));
        float bb = b1[n];
        uint bh  = pk2(bb, 0.0f);
        uint bpk = pk2(bb, bb - lo_f32(bh));
        uint4 u;
        u.x = (g == 0) ? hab : (g == 1) ? lab : (g == 2) ? bpk : 0u;
        u.y = (g == 0) ? hcd : (g == 1) ? lcd : 0u;
        u.z = (g == 0) ? hab : (g == 1) ? lab : 0u;
        u.w = (g == 0) ? hcd : (g == 1) ? lcd : 0u;
        ws[nt * 64 + wl] = u;
    }
    #pragma unroll
    for (int nt = 0; nt < 4; ++nt) {
        #pragma unroll
        for (int mt = 0; mt < 2; ++mt) {
            int c = mt * 16 + l15;
            uint w[4];
            #pragma unroll
            for (int j = 0; j < 4; ++j) {
                float a = w2[(nt * 16 + g * 4 + j) * 32 + c];
                uint t = pk2(a, 0.0f);
                w[j] = pk2(a, a - lo_f32(t));
            }
            ws[(4 + nt * 2 + mt) * 64 + wl] = make_uint4(w[0], w[1], w[2], w[3]);
        }
    }
    #pragma unroll
    for (int mt = 0; mt < 2; ++mt)
        ws[(12 + mt) * 64 + wl] = *(const uint4*)(b2 + 16 * mt + 4 * g);
    #pragma unroll
    for (int mt = 0; mt < 2; ++mt)
        #pragma unroll
        for (int jj = 0; jj < 2; ++jj)
            ws[(14 + mt * 2 + jj) * 64 + wl] =
                *(const uint4*)(w3 + (16 * mt + 4 * g + 2 * jj) * 2);
}

// ---------------- stats kernel: pure VALU, high occupancy ----------------
// One window per thread; wave-private LDS slices; writes split-packed stats
// (uint4) and nrm (f32) at padded stride 32768 per row.
__global__ __launch_bounds__(256) void nsg_stats(
    const float* __restrict__ x, uint4* __restrict__ stp_o,
    float* __restrict__ nrm_o, int N, int M)
{
    __shared__ float s_xw[4][128];
    __shared__ f32x4 s_ck[4][104];

    const int tid = threadIdx.x;
    const int wv  = tid >> 6;
    const int wl  = tid & 63;
    const int u   = blockIdx.x;          // 0..4095
    const int row = u >> 7;              // 128 tiles per row
    const int m0  = (u & 127) * 256 + wv * 64;

    const float* xr = x + (size_t)row * N;
    {
        int g0 = m0 + wl, g1 = m0 + 64 + wl;
        s_xw[wv][wl]      = (g0 < N) ? xr[g0] : 0.0f;
        s_xw[wv][64 + wl] = (g1 < N) ? xr[g1] : 0.0f;
    }
    LDS_FENCE();

    f32x4 myC;
    {
        float S1 = 0.f, S2 = 0.f, S3 = 0.f, S4 = 0.f;
        #pragma unroll
        for (int i = 0; i < 10; ++i) {
            float v = s_xw[wv][wl + i], v2 = v * v;
            S1 += v; S2 += v2; S3 = fmaf(v2, v, S3); S4 = fmaf(v2, v2, S4);
        }
        myC = f32x4{S1, S2, S3, S4};
        s_ck[wv][wl] = myC;
    }
    if (wl < 40) {
        float S1 = 0.f, S2 = 0.f, S3 = 0.f, S4 = 0.f;
        #pragma unroll
        for (int i = 0; i < 10; ++i) {
            float v = s_xw[wv][64 + wl + i], v2 = v * v;
            S1 += v; S2 += v2; S3 = fmaf(v2, v, S3); S4 = fmaf(v2, v2, S4);
        }
        s_ck[wv][64 + wl] = f32x4{S1, S2, S3, S4};
    }
    LDS_FENCE();

    f32x4 ca = s_ck[wv][wl + 10], cb = s_ck[wv][wl + 20];
    f32x4 cc = s_ck[wv][wl + 30], cd = s_ck[wv][wl + 40];
    float S1 = myC[0] + ca[0] + cb[0] + cc[0] + cd[0];
    float S2 = myC[1] + ca[1] + cb[1] + cc[1] + cd[1];
    float S3 = myC[2] + ca[2] + cb[2] + cc[2] + cd[2];
    float S4 = myC[3] + ca[3] + cb[3] + cc[3] + cd[3];
    const float invW = 1.0f / (float)WINDOW;
    float mean = S1 * invW;
    float mu2  = mean * mean;
    float c2m = S2 - (float)WINDOW * mu2;
    float c3m = S3 - 3.0f * mean * S2 + 2.0f * (float)WINDOW * mu2 * mean;
    float c4m = S4 - 4.0f * mean * S3 + 6.0f * mu2 * S2
                  - 3.0f * (float)WINDOW * mu2 * mu2;
    float var    = c2m * (1.0f / (float)(WINDOW - 1));
    float sd     = sqrtf(var) + 1e-6f;
    float inv_sd = 1.0f / sd;
    float inv_sd2 = inv_sd * inv_sd;
    float skew = c3m * invW * inv_sd2 * inv_sd;
    float kurt = c4m * invW * inv_sd2 * inv_sd2;
    float nrm  = (s_xw[wv][wl + 25] - mean) * inv_sd;

    uint4 stp;
    uint h01 = pk2(mean, sd), h23 = pk2(skew, kurt);
    stp.x = h01;
    stp.y = h23;
    stp.z = pk2(mean - lo_f32(h01), sd - hi_f32(h01));
    stp.w = pk2(skew - lo_f32(h23), kurt - hi_f32(h23));

    int m = m0 + wl;
    if (m < M) {
        int w = (row << 15) + m;
        stp_o[w] = stp;
        nrm_o[w] = nrm;
    }
}

// ---------------- MLP kernel: MFMA-dense, fragments amortized ----------------
// 1024 blocks (exactly 4/CU, all co-resident). Each wave: 256 windows =
// 4 qq-groups x 4 sub-iters of 16 windows. Exact-split arithmetic == r8.
__global__ __launch_bounds__(256, 2) void nsg_mlp(
    const uint4* __restrict__ ws, const uint4* __restrict__ stp_i,
    const float* __restrict__ nrm_i, const float* __restrict__ b3,
    float* __restrict__ out, int M)
{
    __shared__ uint4 s_w3[4][64];

    const int tid = threadIdx.x;
    const int wv  = tid >> 6;
    const int wl  = tid & 63;
    const int l15 = wl & 15;
    const int g   = wl >> 4;

    // fragments, loaded once (coalesced, L2-resident)
    short8 A1[4];
    uint4  A2[4][2];
    #pragma unroll
    for (int nt = 0; nt < 4; ++nt) A1[nt] = as_s8(ws[nt * 64 + wl]);
    #pragma unroll
    for (int nt = 0; nt < 4; ++nt)
        #pragma unroll
        for (int mt = 0; mt < 2; ++mt)
            A2[nt][mt] = ws[(4 + nt * 2 + mt) * 64 + wl];
    f32x4 b2r[2];
    #pragma unroll
    for (int mt = 0; mt < 2; ++mt) b2r[mt] = as_f4(ws[(12 + mt) * 64 + wl]);

    if (wv == 0) {
        #pragma unroll
        for (int p = 0; p < 4; ++p) s_w3[p][wl] = ws[(14 + p) * 64 + wl];
    }
    const float b3g = b3[0], b3b = b3[1];
    const uint  K2  = (g == 2) ? 0x3F803F80u : 0u;   // (1.0,1.0) bf16
    const bool  gHi = (g >= 2);
    __syncthreads();

    const int wbase = (int)blockIdx.x * 1024 + wv * 256;  // padded window index
    const int row   = wbase >> 15;                        // constant per wave
    float* outr = out + (size_t)row * M;

    #pragma unroll 1
    for (int qq = 0; qq < 4; ++qq) {
        float ga = 0.f, be = 0.f;
        #pragma unroll
        for (int sub = 0; sub < 4; ++sub) {
            uint4 st = stp_i[wbase + qq * 64 + sub * 16 + l15];
            uint4 bq;
            bq.x = gHi ? K2 : st.x;
            bq.y = gHi ? 0u : st.y;
            bq.z = gHi ? 0u : st.z;
            bq.w = gHi ? 0u : st.w;
            short8 B1 = as_s8(bq);

            f32x4 c2a[2] = { b2r[0], b2r[1] };
            f32x4 c2b[2] = { f32x4{0.f, 0.f, 0.f, 0.f}, f32x4{0.f, 0.f, 0.f, 0.f} };
            #pragma unroll
            for (int nt = 0; nt < 4; ++nt) {
                f32x4 c1 = f32x4{0.f, 0.f, 0.f, 0.f};
                c1 = __builtin_amdgcn_mfma_f32_16x16x32_bf16(A1[nt], B1, c1, 0, 0, 0);
                float r0 = fmaxf(c1[0], 0.f), r1 = fmaxf(c1[1], 0.f);
                float r2 = fmaxf(c1[2], 0.f), r3 = fmaxf(c1[3], 0.f);
                uint t01 = pk2(r0, r1), t23 = pk2(r2, r3);
                float h0 = lo_f32(t01), h1v = hi_f32(t01);
                float h2v = lo_f32(t23), h3v = hi_f32(t23);
                float l0 = r0 - h0, l1 = r1 - h1v, l2 = r2 - h2v, l3 = r3 - h3v;
                uint4 bb, bs;
                bb.x = pk2(h0, l0);  bb.y = pk2(h1v, l1);
                bb.z = pk2(h2v, l2); bb.w = pk2(h3v, l3);
                bs.x = pk2(l0, h0);  bs.y = pk2(l1, h1v);
                bs.z = pk2(l2, h2v); bs.w = pk2(l3, h3v);
                short8 B2 = as_s8(bb), B2s = as_s8(bs);
                #pragma unroll
                for (int mt = 0; mt < 2; ++mt) {
                    c2a[mt] = __builtin_amdgcn_mfma_f32_16x16x32_bf16(as_s8(A2[nt][mt]), B2,  c2a[mt], 0, 0, 0);
                    c2b[mt] = __builtin_amdgcn_mfma_f32_16x16x32_bf16(as_s8(A2[nt][mt]), B2s, c2b[mt], 0, 0, 0);
                }
            }
            float pg = 0.f, pb = 0.f;
            #pragma unroll
            for (int mt = 0; mt < 2; ++mt) {
                #pragma unroll
                for (int jj = 0; jj < 2; ++jj) {
                    f32x4 wq = as_f4(s_w3[mt * 2 + jj][wl]);
                    #pragma unroll
                    for (int h = 0; h < 2; ++h) {
                        float P = fmaxf(c2a[mt][jj * 2 + h] + c2b[mt][jj * 2 + h], 0.f);
                        pg = fmaf(P, wq[h * 2 + 0], pg);
                        pb = fmaf(P, wq[h * 2 + 1], pb);
                    }
                }
            }
            pg += __shfl_xor(pg, 16);
            pb += __shfl_xor(pb, 16);
            pg += __shfl_xor(pg, 32);
            pb += __shfl_xor(pb, 32);
            if (g == sub) { ga = pg; be = pb; }
        }
        int w = wbase + qq * 64 + wl;
        int m = w & 32767;
        if (m < M)
            outr[m] = fmaf(nrm_i[w], ga + b3g, be + b3b);
    }
}

extern "C" void kernel_launch(void* const* d_in, const int* in_sizes, int n_in,
                              void* d_out, int out_size, void* d_ws, size_t ws_size,
                              hipStream_t stream) {
    const float* x  = (const float*)d_in[0];
    const float* w1 = (const float*)d_in[1];
    const float* b1 = (const float*)d_in[2];
    const float* w2 = (const float*)d_in[3];
    const float* b2 = (const float*)d_in[4];
    const float* w3 = (const float*)d_in[5];
    const float* b3 = (const float*)d_in[6];
    float* out = (float*)d_out;

    const int N = 32768;
    const int M = N - WINDOW + 1;            // 32719

    uint4* ws    = (uint4*)d_ws;                                   // frags: 18*64 uint4
    uint4* stp   = (uint4*)((char*)d_ws + 64 * 1024);              // 32*32768 uint4 = 16 MB
    float* nrm   = (float*)((char*)d_ws + 64 * 1024 + (size_t)16 * 1024 * 1024); // 4 MB

    nsg_prep<<<dim3(1), dim3(64), 0, stream>>>(w1, b1, w2, b2, w3, ws);
    nsg_stats<<<dim3(4096), dim3(256), 0, stream>>>(x, stp, nrm, N, M);
    nsg_mlp<<<dim3(1024), dim3(256), 0, stream>>>(ws, stp, nrm, b3, out, M);
}